// Round 7
// baseline (25.758 us; speedup 1.0000x reference)
//
#include <hip/hip_runtime.h>

// Problem constants from the reference:
//   B=256, A=128, D=8, F=512 (bonds input is UNUSED by the reference)
#define B_ 256
#define A_ 128
#define D_ 8
#define F_ 512
#define FC 32                 // feature-chunk (floats) per buffer
#define CPB 2                 // chunks per block (double-buffered)
#define NPAIR (F_ / (FC*CPB)) // 8 chunk-pairs per batch
#define THREADS 256
#define NXCD 8
#define NBLK (B_ * NPAIR)     // 2048 blocks

typedef float vfloat4 __attribute__((ext_vector_type(4)));

typedef __attribute__((address_space(3))) void        as3_void;
typedef const __attribute__((address_space(1))) void  as1_void;

// Direct global->LDS 16B copy. LDS dest is wave-uniform base + lane*16
// (our linear layout satisfies this); global source may be per-lane.
__device__ __forceinline__ void gload_lds16(const void* g, void* l) {
    __builtin_amdgcn_global_load_lds((as1_void*)g, (as3_void*)l, 16, 0, 0);
}

__device__ __forceinline__ void compute_chunk(
    const float* __restrict__ slab,   // [A_][FC] in LDS
    const int*   __restrict__ eds,    // [A_][D_] in LDS
    float*       __restrict__ obase,  // out + b*A_*F_ + fc0
    int t)
{
#pragma unroll
    for (int k = 0; k < (A_ * FC / 4) / THREADS; ++k) {
        const int o = k * THREADS + t;
        const int a = o >> 3;                 // / (FC/4 == 8)
        const int c = (o & 7) * 4;

        int e[D_];
        int degree = 0;
#pragma unroll
        for (int d = 0; d < D_; ++d) {
            e[d] = eds[a * D_ + d];           // broadcast within 8-lane group
            degree += (e[d] >= 0) ? 1 : 0;
        }

        vfloat4 acc = *reinterpret_cast<const vfloat4*>(slab + a * FC + c);
#pragma unroll
        for (int d = 0; d < D_; ++d) {
            const int row = (e[d] >= 0) ? e[d] : a;  // invalid -> self (identity)
            const vfloat4 v = *reinterpret_cast<const vfloat4*>(slab + row * FC + c);
            acc.x = fmaxf(acc.x, v.x);
            acc.y = fmaxf(acc.y, v.y);
            acc.z = fmaxf(acc.z, v.z);
            acc.w = fmaxf(acc.w, v.w);
        }

        vfloat4 r = acc;
        if (degree == 0) r = (vfloat4)(0.f);
        *reinterpret_cast<vfloat4*>(obase + a * F_ + c) = r;
    }
}

// One block per (batch, chunk-pair). Issue ALL global->LDS loads up front
// (edges + slab0 + slab1 = 9 per thread), then a COUNTED s_waitcnt vmcnt(4)
// releases chunk-0 compute while chunk-1's 4 loads stay in flight — its HBM
// latency hides under chunk-0's LDS-gather + stores. Second chunk syncs with
// a plain __syncthreads() (vmcnt(0) drain).
__global__ __launch_bounds__(THREADS) void NeuralGraphPool_kernel(
    const float* __restrict__ atoms,   // [B, A, F]
    const int*   __restrict__ edges,   // [B, A, D]
    float*       __restrict__ out)     // [B, A, F]
{
    __shared__ float slab[CPB][A_ * FC];  // 2 x 16 KB
    __shared__ int   eds[A_ * D_];        // 4 KB (shared by both chunks)

    // XCD swizzle (2048 = 8*256, bijective): one batch's pairs stay on one XCD.
    const int hw = blockIdx.x;
    const int p  = (hw & (NXCD - 1)) * (NBLK / NXCD) + (hw >> 3);

    const int b   = p >> 3;                       // / NPAIR
    const int fc0 = (p & (NPAIR - 1)) * (FC * CPB);
    const int t   = threadIdx.x;

    const float* __restrict__ abase = atoms + (size_t)b * (A_ * F_) + fc0;
    float*       __restrict__ obase = out   + (size_t)b * (A_ * F_) + fc0;

    // --- issue: edges (1), slab0 (4), slab1 (4) per thread ---
    gload_lds16(edges + (size_t)b * (A_ * D_) + t * 4, eds + t * 4);
#pragma unroll
    for (int j = 0; j < (A_ * FC / 4) / THREADS; ++j) {
        const int fi = j * THREADS + t;
        const int a  = fi >> 3;
        const int c  = fi & 7;
        gload_lds16(abase + a * F_ + c * 4, &slab[0][fi * 4]);
    }
#pragma unroll
    for (int j = 0; j < (A_ * FC / 4) / THREADS; ++j) {
        const int fi = j * THREADS + t;
        const int a  = fi >> 3;
        const int c  = fi & 7;
        gload_lds16(abase + FC + a * F_ + c * 4, &slab[1][fi * 4]);
    }

    // Counted wait: oldest 5 (edges + slab0) done; slab1's 4 still in flight.
    asm volatile("s_waitcnt vmcnt(4)" ::: "memory");
    __builtin_amdgcn_s_barrier();
    __builtin_amdgcn_sched_barrier(0);

    compute_chunk(slab[0], eds, obase, t);

    __syncthreads();   // drains vmcnt(0): slab1 ready

    compute_chunk(slab[1], eds, obase + FC, t);
}

extern "C" void kernel_launch(void* const* d_in, const int* in_sizes, int n_in,
                              void* d_out, int out_size, void* d_ws, size_t ws_size,
                              hipStream_t stream) {
    const float* atoms = (const float*)d_in[0];
    // d_in[1] = bonds: unused by the reference computation
    const int*   edges = (const int*)d_in[2];
    float*       out   = (float*)d_out;

    dim3 grid(NBLK);     // 2048 blocks
    dim3 block(THREADS);
    hipLaunchKernelGGL(NeuralGraphPool_kernel, grid, block, 0, stream,
                       atoms, edges, out);
}